// Round 8
// baseline (49.866 us; speedup 1.0000x reference)
//
#include <hip/hip_runtime.h>
#include <hip/hip_bf16.h>

// out[b,v] = dot(OT[b, pid[v], :], W[v, :]) + bias[v]
// B=32, Q=180, H=768, V=19004. fp32 in/out, bf16 MFMA inside.
#define BB 32
#define QQ 180
#define HH 768
#define VV 19004
#define VB 64
#define KH 384       // K per half
#define SB 19008     // res stride (pos dim)
#define MAXDESC 480
#define STRIDE 392   // OT LDS row stride in bf16 elems (384 + 8 pad = 784 B)

// ws layout (bytes)
#define WS_NTOT   2048     // 1 int
#define WS_SORTED 4096     // VV ints
#define WS_POSOF  81920    // VV ints
#define WS_DESC   159744   // 480 int4
#define WS_RES    167936   // 2 * 32 * 19008 * 4 = 4,866,048 B

typedef __attribute__((ext_vector_type(8))) short short8v;  // 8 bf16 (4 VGPR)
typedef __attribute__((ext_vector_type(4))) float f32x4;

__device__ __forceinline__ short f2bf(float f) {  // RNE fp32->bf16
    unsigned u = __builtin_bit_cast(unsigned, f);
    u += 0x7FFFu + ((u >> 16) & 1u);
    return (short)(u >> 16);
}

// ---------- fused pre-pass: histogram + scan + desc + scatter, 1 block ----------
__global__ void prep_k(const int* __restrict__ pid, int* __restrict__ sorted,
                       int* __restrict__ posOf, int4* __restrict__ desc,
                       int* __restrict__ ntot) {
    __shared__ int cnt[256];
    __shared__ int sc[256];
    __shared__ int sn[256];
    __shared__ int cur[256];
    const int t = threadIdx.x;  // 1024 threads
    if (t < 256) cnt[t] = 0;
    __syncthreads();
    for (int v = t; v < VV; v += 1024) atomicAdd(&cnt[pid[v]], 1);
    __syncthreads();
    if (t < 256) sc[t] = cnt[t];
    __syncthreads();
    for (int off = 1; off < 256; off <<= 1) {
        int add = (t < 256 && t >= off) ? sc[t - off] : 0;
        __syncthreads();
        if (t < 256) sc[t] += add;
        __syncthreads();
    }
    if (t < 256) {
        const int c = cnt[t];
        cur[t] = sc[t] - c;                      // q start
        sn[t] = (c + VB - 1) / VB;               // chunks for this q
    }
    __syncthreads();
    for (int off = 1; off < 256; off <<= 1) {
        int add = (t < 256 && t >= off) ? sn[t - off] : 0;
        __syncthreads();
        if (t < 256) sn[t] += add;
        __syncthreads();
    }
    if (t < QQ) {
        const int c = cnt[t];
        const int nch = (c + VB - 1) / VB;
        const int cb = sn[t] - nch;
        const int qs = cur[t];
        for (int j = 0; j < nch; ++j)
            desc[cb + j] = make_int4(t, qs + j * VB, min(VB, c - j * VB), 0);
    }
    if (t == 255) *ntot = sn[255];
    __syncthreads();
    for (int v = t; v < VV; v += 1024) {
        const int q = pid[v];
        const int pos = atomicAdd(&cur[q], 1);   // LDS atomic: fast
        sorted[pos] = v;
        posOf[v] = pos;                          // coalesced write
    }
}

// ---------- main: MFMA 16x16x32 bf16, block = (chunk, K-half) ----------
// A = OT (M=b), B = W (N=v). 4 waves; wave w owns v-tile w (16 v's), both
// b-tiles, K=384 (12 steps x2 MFMA). OT half staged once in LDS as bf16;
// W burst-loaded (24 outstanding float4/lane). Full-line pos-space stores.
__launch_bounds__(256)
__global__ void main_k(const float* __restrict__ OT, const float* __restrict__ W,
                       const int* __restrict__ sorted, const int4* __restrict__ desc,
                       const int* __restrict__ ntot, float* __restrict__ res) {
    const int nt = *ntot;
    const int bid = blockIdx.x;
    const int ci = bid >> 1;
    if (ci >= nt) return;
    const int kh = bid & 1;
    const int4 d = desc[ci];
    const int q     = __builtin_amdgcn_readfirstlane(d.x);
    const int start = __builtin_amdgcn_readfirstlane(d.y);
    const int len   = __builtin_amdgcn_readfirstlane(d.z);
    const int tid = threadIdx.x;

    __shared__ short OTlds[BB * STRIDE];  // 25,088 B

    // stage OT[0..31][q][kh*384 .. +384) as bf16 (coalesced fp32 reads)
    {
        const int r = tid >> 3;   // b row 0..31
        const int o = tid & 7;    // octet
        const float* src = OT + ((size_t)r * QQ + q) * HH + kh * KH + o * 8;
        short* dst = &OTlds[r * STRIDE + o * 8];
#pragma unroll
        for (int it = 0; it < 6; ++it) {
            const float4 f0 = *(const float4*)(src + it * 64);
            const float4 f1 = *(const float4*)(src + it * 64 + 4);
            short8v s;
            s[0] = f2bf(f0.x); s[1] = f2bf(f0.y); s[2] = f2bf(f0.z); s[3] = f2bf(f0.w);
            s[4] = f2bf(f1.x); s[5] = f2bf(f1.y); s[6] = f2bf(f1.z); s[7] = f2bf(f1.w);
            *(short8v*)(dst + it * 64) = s;
        }
    }

    const int lane = tid & 63;
    const int w = tid >> 6;           // v-tile
    const int co = lane & 15;         // frag col
    const int kq = lane >> 4;         // k-quad
    const int vl = 16 * w + co;       // v-local in chunk
    const int vg = sorted[start + min(vl, len - 1)];
    const float4* wp4 = (const float4*)(W + (size_t)vg * HH + kh * KH + kq * 8);
    const short* a0 = &OTlds[co * STRIDE + kq * 8];

    // burst: issue ALL W loads before any use (24 outstanding 16B/lane)
    float4 wf[24];
#pragma unroll
    for (int kk = 0; kk < 12; ++kk) {
        wf[2 * kk]     = wp4[kk * 8];
        wf[2 * kk + 1] = wp4[kk * 8 + 1];
    }

    __syncthreads();

    f32x4 acc0 = {0.f, 0.f, 0.f, 0.f};
    f32x4 acc1 = {0.f, 0.f, 0.f, 0.f};
#pragma unroll
    for (int kk = 0; kk < 12; ++kk) {
        const float4 wf0 = wf[2 * kk];
        const float4 wf1 = wf[2 * kk + 1];
        short8v bf;
        bf[0] = f2bf(wf0.x); bf[1] = f2bf(wf0.y); bf[2] = f2bf(wf0.z); bf[3] = f2bf(wf0.w);
        bf[4] = f2bf(wf1.x); bf[5] = f2bf(wf1.y); bf[6] = f2bf(wf1.z); bf[7] = f2bf(wf1.w);
        const short8v a0v = *(const short8v*)(a0 + kk * 32);
        const short8v a1v = *(const short8v*)(a0 + 16 * STRIDE + kk * 32);
        acc0 = __builtin_amdgcn_mfma_f32_16x16x32_bf16(a0v, bf, acc0, 0, 0, 0);
        acc1 = __builtin_amdgcn_mfma_f32_16x16x32_bf16(a1v, bf, acc1, 0, 0, 0);
    }

    // C[row=b][col=v]: row = (lane>>4)*4 + reg, col = lane&15  (m89-verified)
    if (vl < len) {
        float* rp = res + (size_t)(kh * BB) * SB + start + vl;
#pragma unroll
        for (int r2 = 0; r2 < 4; ++r2) {
            rp[(size_t)(kq * 4 + r2) * SB]      = acc0[r2];
            rp[(size_t)(16 + kq * 4 + r2) * SB] = acc1[r2];
        }
    }
}

// ---------- combine: gather res via posOf (L2), coalesced out writes ----------
__global__ void combine_k(const float* __restrict__ res, const int* __restrict__ posOf,
                          const float* __restrict__ bias, float* __restrict__ out) {
    const int v = blockIdx.x * 256 + threadIdx.x;
    if (v >= VV) return;
    const int b = blockIdx.y;
    const int pos = posOf[v];
    const float s = res[(size_t)b * SB + pos] + res[(size_t)(BB + b) * SB + pos];
    out[(size_t)b * VV + v] = s + bias[v];
}

extern "C" void kernel_launch(void* const* d_in, const int* in_sizes, int n_in,
                              void* d_out, int out_size, void* d_ws, size_t ws_size,
                              hipStream_t stream) {
    const float* OT   = (const float*)d_in[0];  // [B,Q,H]
    const float* W    = (const float*)d_in[1];  // [V,H]
    const float* bias = (const float*)d_in[2];  // [V]
    const int*   pid  = (const int*)d_in[3];    // [V]
    float* out = (float*)d_out;                 // [B,V]

    char* ws = (char*)d_ws;
    int*   ntot   = (int*)(ws + WS_NTOT);
    int*   sorted = (int*)(ws + WS_SORTED);
    int*   posOf  = (int*)(ws + WS_POSOF);
    int4*  desc   = (int4*)(ws + WS_DESC);
    float* res    = (float*)(ws + WS_RES);

    prep_k<<<1, 1024, 0, stream>>>(pid, sorted, posOf, desc, ntot);

    main_k<<<2 * MAXDESC, 256, 0, stream>>>(OT, W, sorted, desc, ntot, res);

    combine_k<<<dim3((VV + 255) / 256, BB), 256, 0, stream>>>(res, posOf, bias, out);
}